// Round 13
// baseline (389.869 us; speedup 1.0000x reference)
//
#include <hip/hip_runtime.h>

#define FEAT 83
#define DIMF 64
#define LAT  32
#define THREADS 256         // 4 waves per block
#define TROWS 128           // rows per tile: 4 waves x 32 rows
#define GRID 512            // 2 blocks/CU x 256 CU; grid-stride over tiles

typedef __attribute__((ext_vector_type(8))) short bf16x8;
typedef __attribute__((ext_vector_type(4))) float f32x4;
typedef __attribute__((ext_vector_type(4))) unsigned u32x4;

// d_ws image (shorts): exact LDS layout, built once by prep kernel
//  bt1: [64 h-cols][96 k] (k 83..95 zeroed)   bt2: [32][64]   bt3: [32][32]
#define WT1H 0
#define WT1L 6144
#define WT2H 12288
#define WT2L 14336
#define WT3H 16384
#define WT3L 17408
#define WS_SHORTS 18432     // 36864 B

// LDS map (bytes):
//  [0,36864)   weight image, staged ONCE per block (one barrier, then inert)
//  [36864,...) per-wave SINGLE x chunk (10624 B): register prefetch of tile
//              t+1 is the second buffer. After frag build of tile t, the
//              wave's 4KB packed h/g scratch overlays its own chunk
//              (same-wave DS order) -> NO barriers in the tile loop.
#define SM_BYTES (36864 + 4 * 10624)   // 79360 B -> 2 blocks/CU = 8 waves/CU

__device__ __forceinline__ short f2b(float f) {   // fp32 -> bf16 RNE
    unsigned u = __float_as_uint(f);
    u += 0x7fffu + ((u >> 16) & 1u);
    return (short)(u >> 16);
}
__device__ __forceinline__ float b2f(short h) {   // bf16 -> fp32 exact
    return __uint_as_float(((unsigned)(unsigned short)h) << 16);
}

// ---- K1: one-time weight hi/lo split into d_ws (tiny, off hot path) ----
__global__ void prep_weights(const float* __restrict__ W1,
                             const float* __restrict__ Wh0,
                             const float* __restrict__ Wh1,
                             short* __restrict__ ws)
{
    const int stride = gridDim.x * blockDim.x;
    const int tid = blockIdx.x * blockDim.x + threadIdx.x;
    for (int idx = tid; idx < 64 * 96; idx += stride) {       // W1^T + K-pad
        int c = idx / 96, k = idx - c * 96;
        float w = (k < FEAT) ? W1[k * 64 + c] : 0.f;
        short hi = f2b(w);
        ws[WT1H + idx] = hi;
        ws[WT1L + idx] = f2b(w - b2f(hi));
    }
    for (int idx = tid; idx < 32 * 64; idx += stride) {       // Wh0^T
        int c = idx >> 6, k = idx & 63;
        float w = Wh0[k * 32 + c];
        short hi = f2b(w);
        ws[WT2H + idx] = hi;
        ws[WT2L + idx] = f2b(w - b2f(hi));
    }
    for (int idx = tid; idx < 32 * 32; idx += stride) {       // Wh1^T
        int c = idx >> 5, k = idx & 31;
        float w = Wh1[k * 32 + c];
        short hi = f2b(w);
        ws[WT3H + idx] = hi;
        ws[WT3L + idx] = f2b(w - b2f(hi));
    }
}

// unpack 8 packed (hi<<16|lo) dwords -> two bf16x8 fragments
__device__ __forceinline__ void unpack8(const unsigned* p, bf16x8& hi, bf16x8& lo) {
    union { bf16x8 v; unsigned u[4]; } H, L;
    #pragma unroll
    for (int d = 0; d < 4; ++d) {
        H.u[d] = __builtin_amdgcn_perm(p[2 * d + 1], p[2 * d], 0x07060302u);
        L.u[d] = __builtin_amdgcn_perm(p[2 * d + 1], p[2 * d], 0x05040100u);
    }
    hi = H.v; lo = L.v;
}

__global__ __launch_bounds__(THREADS, 2)
void material_encoder_kernel(const float* __restrict__ inp,
                             const float* __restrict__ shiftp,
                             const short* __restrict__ ws,
                             const float* __restrict__ b1,
                             const float* __restrict__ bh0,
                             const float* __restrict__ bh1,
                             float* __restrict__ out,
                             int nrows)
{
    __shared__ __align__(16) char smb[SM_BYTES];
    short* sm = (short*)smb;           // weight image (shorts) at offset 0

    const int t    = threadIdx.x;
    const int lane = t & 63;
    const int wv   = t >> 6;
    const int lr   = lane & 15;        // A-row / B-col / C-col index
    const int lq   = (lane >> 4) & 3;  // lane quarter

    // ---- stage weights ONCE per block (linear b128, conflict-free) ----
    {
        const f32x4* __restrict__ wsrc = (const f32x4*)ws;
        f32x4* wdst = (f32x4*)smb;
        #pragma unroll
        for (int it = 0; it < 9; ++it)                  // 9*256*16B = 36864B
            wdst[it * THREADS + t] = wsrc[it * THREADS + t];
    }

    // biases per lane (L1/L2-cached)
    float bias1[4], bias2[2], bias3[2];
    #pragma unroll
    for (int n = 0; n < 4; ++n) bias1[n] = b1[lr + 16 * n];
    #pragma unroll
    for (int n = 0; n < 2; ++n) { bias2[n] = bh0[lr + 16 * n]; bias3[n] = bh1[lr + 16 * n]; }
    const float sh = shiftp[0];

    __syncthreads();   // weights ready -- the ONLY barrier in this kernel

    const int ntiles = nrows / TROWS;        // 15625
    const int osz    = nrows * LAT;          // 64M, fits int
    float*    xw  = (float*)(smb + 36864 + wv * 10624);   // single chunk/wave
    unsigned* scr = (unsigned*)xw;           // overlays xw after frag build

    int tile = blockIdx.x;
    // ---- prologue: issue coalesced x loads for first tile ----
    f32x4 xreg[11];
    {
        const f32x4* __restrict__ src4 = (const f32x4*)
            (inp + (long long)tile * (TROWS * FEAT) + wv * (32 * FEAT));
        #pragma unroll
        for (int r = 0; r < 10; ++r) xreg[r] = src4[r * 64 + lane];
        if (lane < 24) xreg[10] = src4[640 + lane];
    }

    for (;;) {
        // ---- ds_write tile t (waits on its global loads); WAR vs scratch
        //      reads of tile t-1 is safe: same-wave DS program order ----
        {
            f32x4* xdst = (f32x4*)xw;
            #pragma unroll
            for (int r = 0; r < 10; ++r) xdst[r * 64 + lane] = xreg[r];
            if (lane < 24) xdst[640 + lane] = xreg[10];
        }

        // ---- A fragments (x+shift) hi/lo from own chunk; nz mask on raw x ----
        // frag layout (16x16x32): row = lr, k = 8*lq + i (+32*s); trunc-hi split
        // k>=83 clamps to 82: duplicate finite x * zeroed W-pad -> 0
        bf16x8 a1h[2][3], a1l[2][3];
        float nzm[2];
        #pragma unroll
        for (int m = 0; m < 2; ++m) {
            const float* __restrict__ xr = xw + (16 * m + lr) * FEAT;
            float nz = 0.f;
            #pragma unroll
            for (int s = 0; s < 3; ++s) {
                const int k0 = 32 * s + 8 * lq;
                bf16x8 fh, fl;
                #pragma unroll
                for (int i = 0; i < 8; ++i) {
                    int kk = k0 + i;
                    kk = (kk < FEAT) ? kk : (FEAT - 1);
                    const float x = xr[kk];
                    nz = fmaxf(nz, fabsf(x));
                    const float xs = x + sh;
                    const unsigned u = __float_as_uint(xs);
                    fh[i] = (short)(u >> 16);            // truncation hi
                    fl[i] = f2b(xs - __uint_as_float(u & 0xffff0000u));
                }
                a1h[m][s] = fh;
                a1l[m][s] = fl;
            }
            nzm[m] = nz;
        }
        #pragma unroll
        for (int m = 0; m < 2; ++m) {     // full-row max across the 4 k-quarters
            nzm[m] = fmaxf(nzm[m], __shfl_xor(nzm[m], 16));
            nzm[m] = fmaxf(nzm[m], __shfl_xor(nzm[m], 32));
        }

        // ---- issue tile t+1 x loads NOW (hide HBM latency under compute) ----
        const int next = tile + GRID;
        const bool has_next = next < ntiles;
        if (has_next) {
            const f32x4* __restrict__ src4 = (const f32x4*)
                (inp + (long long)next * (TROWS * FEAT) + wv * (32 * FEAT));
            #pragma unroll
            for (int r = 0; r < 10; ++r) xreg[r] = src4[r * 64 + lane];
            if (lane < 24) xreg[10] = src4[640 + lane];
        }

        // ---- layer 1: 2(M) x 4(N) x 3(K) x 3 split-terms ----
        f32x4 acc[2][4];
        #pragma unroll
        for (int m = 0; m < 2; ++m)
            #pragma unroll
            for (int n = 0; n < 4; ++n)
                acc[m][n] = (f32x4){bias1[n], bias1[n], bias1[n], bias1[n]};

        #pragma unroll
        for (int s = 0; s < 3; ++s)
            #pragma unroll
            for (int n = 0; n < 4; ++n) {
                bf16x8 bh = *(const bf16x8*)&sm[WT1H + (lr + 16 * n) * 96 + 32 * s + 8 * lq];
                bf16x8 bl = *(const bf16x8*)&sm[WT1L + (lr + 16 * n) * 96 + 32 * s + 8 * lq];
                #pragma unroll
                for (int m = 0; m < 2; ++m) {
                    acc[m][n] = __builtin_amdgcn_mfma_f32_16x16x32_bf16(a1h[m][s], bh, acc[m][n], 0, 0, 0);
                    acc[m][n] = __builtin_amdgcn_mfma_f32_16x16x32_bf16(a1l[m][s], bh, acc[m][n], 0, 0, 0);
                    acc[m][n] = __builtin_amdgcn_mfma_f32_16x16x32_bf16(a1h[m][s], bl, acc[m][n], 0, 0, 0);
                }
            }

        // ---- layer 2 via packed scratch overlaying own dead x chunk ----
        f32x4 acc2[2][2];
        #pragma unroll
        for (int m = 0; m < 2; ++m)
            #pragma unroll
            for (int n = 0; n < 2; ++n)
                acc2[m][n] = (f32x4){bias2[n], bias2[n], bias2[n], bias2[n]};

        #pragma unroll
        for (int s = 0; s < 2; ++s) {
            #pragma unroll
            for (int m = 0; m < 2; ++m)
                #pragma unroll
                for (int np = 0; np < 2; ++np)
                    #pragma unroll
                    for (int r = 0; r < 4; ++r) {
                        const float hv = fmaxf(acc[m][2 * s + np][r], 0.f);
                        const unsigned u = __float_as_uint(hv);
                        const unsigned hiu = u & 0xffff0000u;
                        const unsigned lo16 =
                            (unsigned short)f2b(hv - __uint_as_float(hiu));
                        scr[(16 * m + 4 * lq + r) * 32 + lr + 16 * np] = hiu | lo16;
                    }
            bf16x8 a2h[2], a2l[2];
            #pragma unroll
            for (int m = 0; m < 2; ++m) {
                unsigned p[8];
                *(u32x4*)&p[0] = *(const u32x4*)&scr[(lr + 16 * m) * 32 + 8 * lq];
                *(u32x4*)&p[4] = *(const u32x4*)&scr[(lr + 16 * m) * 32 + 8 * lq + 4];
                unpack8(p, a2h[m], a2l[m]);
            }
            #pragma unroll
            for (int n = 0; n < 2; ++n) {
                bf16x8 bh = *(const bf16x8*)&sm[WT2H + (lr + 16 * n) * 64 + 32 * s + 8 * lq];
                bf16x8 bl = *(const bf16x8*)&sm[WT2L + (lr + 16 * n) * 64 + 32 * s + 8 * lq];
                #pragma unroll
                for (int m = 0; m < 2; ++m) {
                    acc2[m][n] = __builtin_amdgcn_mfma_f32_16x16x32_bf16(a2h[m], bh, acc2[m][n], 0, 0, 0);
                    acc2[m][n] = __builtin_amdgcn_mfma_f32_16x16x32_bf16(a2l[m], bh, acc2[m][n], 0, 0, 0);
                    acc2[m][n] = __builtin_amdgcn_mfma_f32_16x16x32_bf16(a2h[m], bl, acc2[m][n], 0, 0, 0);
                }
            }
        }

        // ---- layer 3: g through the same scratch (same-wave order) ----
        f32x4 acc3[2][2];
        #pragma unroll
        for (int m = 0; m < 2; ++m)
            #pragma unroll
            for (int n = 0; n < 2; ++n)
                acc3[m][n] = (f32x4){bias3[n], bias3[n], bias3[n], bias3[n]};

        #pragma unroll
        for (int m = 0; m < 2; ++m)
            #pragma unroll
            for (int n = 0; n < 2; ++n)
                #pragma unroll
                for (int r = 0; r < 4; ++r) {
                    const float gv = fmaxf(acc2[m][n][r], 0.f);
                    const unsigned u = __float_as_uint(gv);
                    const unsigned hiu = u & 0xffff0000u;
                    const unsigned lo16 =
                        (unsigned short)f2b(gv - __uint_as_float(hiu));
                    scr[(16 * m + 4 * lq + r) * 32 + lr + 16 * n] = hiu | lo16;
                }
        {
            bf16x8 a3h[2], a3l[2];
            #pragma unroll
            for (int m = 0; m < 2; ++m) {
                unsigned p[8];
                *(u32x4*)&p[0] = *(const u32x4*)&scr[(lr + 16 * m) * 32 + 8 * lq];
                *(u32x4*)&p[4] = *(const u32x4*)&scr[(lr + 16 * m) * 32 + 8 * lq + 4];
                unpack8(p, a3h[m], a3l[m]);
            }
            #pragma unroll
            for (int n = 0; n < 2; ++n) {
                bf16x8 bh = *(const bf16x8*)&sm[WT3H + (lr + 16 * n) * 32 + 8 * lq];
                bf16x8 bl = *(const bf16x8*)&sm[WT3L + (lr + 16 * n) * 32 + 8 * lq];
                #pragma unroll
                for (int m = 0; m < 2; ++m) {
                    acc3[m][n] = __builtin_amdgcn_mfma_f32_16x16x32_bf16(a3h[m], bh, acc3[m][n], 0, 0, 0);
                    acc3[m][n] = __builtin_amdgcn_mfma_f32_16x16x32_bf16(a3l[m], bh, acc3[m][n], 0, 0, 0);
                    acc3[m][n] = __builtin_amdgcn_mfma_f32_16x16x32_bf16(a3h[m], bl, acc3[m][n], 0, 0, 0);
                }
            }
        }

        // ---- relu + row L2 norm (reduce over lr lanes) + mask via shfl ----
        float er[2][2][4];
        float ssq[2][4];
        #pragma unroll
        for (int m = 0; m < 2; ++m)
            #pragma unroll
            for (int r = 0; r < 4; ++r) ssq[m][r] = 0.f;
        #pragma unroll
        for (int m = 0; m < 2; ++m)
            #pragma unroll
            for (int n = 0; n < 2; ++n)
                #pragma unroll
                for (int r = 0; r < 4; ++r) {
                    float e = fmaxf(acc3[m][n][r], 0.f);
                    er[m][n][r] = e;
                    ssq[m][r] = fmaf(e, e, ssq[m][r]);
                }
        #pragma unroll
        for (int msk = 1; msk <= 8; msk <<= 1)
            #pragma unroll
            for (int m = 0; m < 2; ++m)
                #pragma unroll
                for (int r = 0; r < 4; ++r)
                    ssq[m][r] += __shfl_xor(ssq[m][r], msk);

        float sc[2][4];
        #pragma unroll
        for (int m = 0; m < 2; ++m)
            #pragma unroll
            for (int r = 0; r < 4; ++r) {
                const float mkv = __shfl(nzm[m], 4 * lq + r);  // rowmax(16m+4lq+r)
                // rsqrt(max(ss,1e-24)) == 1/max(sqrt(ss),1e-12)
                sc[m][r] = (mkv != 0.f) ? rsqrtf(fmaxf(ssq[m][r], 1e-24f)) : 0.f;
            }

        // ---- store 3 copies (quarter-wave 64B segments) ----
        const int Rw = tile * TROWS + wv * 32;
        float* __restrict__ ob = out + (long long)Rw * LAT;
        #pragma unroll
        for (int m = 0; m < 2; ++m)
            #pragma unroll
            for (int r = 0; r < 4; ++r) {
                const int ro = (16 * m + 4 * lq + r) * LAT;
                #pragma unroll
                for (int n = 0; n < 2; ++n) {
                    const float vv = er[m][n][r] * sc[m][r];
                    const int cc = ro + lr + 16 * n;
                    ob[cc]           = vv;
                    ob[osz + cc]     = vv;
                    ob[2 * osz + cc] = vv;
                }
            }

        if (!has_next) break;
        tile = next;
    }
}

extern "C" void kernel_launch(void* const* d_in, const int* in_sizes, int n_in,
                              void* d_out, int out_size, void* d_ws, size_t ws_size,
                              hipStream_t stream) {
    const float* inp    = (const float*)d_in[0];
    const float* shiftp = (const float*)d_in[1];
    const float* W1     = (const float*)d_in[2];
    const float* b1     = (const float*)d_in[3];
    const float* Wh0    = (const float*)d_in[4];
    const float* bh0    = (const float*)d_in[5];
    const float* Wh1    = (const float*)d_in[6];
    const float* bh1    = (const float*)d_in[7];
    float* out = (float*)d_out;
    short* ws  = (short*)d_ws;

    const int nrows  = in_sizes[0] / FEAT;     // 2,000,000 = 128 * 15625
    const int ntiles = nrows / TROWS;
    const int grid   = (ntiles < GRID) ? ntiles : GRID;

    prep_weights<<<dim3(24), dim3(256), 0, stream>>>(W1, Wh0, Wh1, ws);
    material_encoder_kernel<<<dim3(grid), dim3(THREADS), 0, stream>>>(
        inp, shiftp, ws, b1, bh0, bh1, out, nrows);
}

// Round 14
// 264.714 us; speedup vs baseline: 1.4728x; 1.4728x over previous
//
#include <hip/hip_runtime.h>

#define FEAT 83
#define DIMF 64
#define LAT  32
#define THREADS 256
#define RPB  128            // rows per block: 4 waves x 32 rows

typedef __attribute__((ext_vector_type(8))) short bf16x8;
typedef __attribute__((ext_vector_type(4))) float f32x4;
typedef __attribute__((ext_vector_type(4))) unsigned u32x4;

// d_ws image (shorts): exact LDS layout, built once by prep kernel
//  bt1: [64 h-cols][96 k] (k 83..95 zeroed)   bt2: [32][64]   bt3: [32][32]
#define WT1H 0
#define WT1L 6144
#define WT2H 12288
#define WT2L 14336
#define WT3H 16384
#define WT3L 17408
#define WS_SHORTS 18432     // 36864 B

// LDS map (bytes), PHASED:
//  phase A: x-tile fp32 linear, wave-local chunks: wave wv at [wv*10624,(wv+1)*10624)
//           (each wave stages & reads ONLY its own chunk -> same-wave DS order,
//            no barrier needed for the x path)
//  phase B (after bar1): weight image overlays [0,36864)
//  [36864,53248)  4 x 4096B per-wave packed scratch (used after bar2; x dead)
//  [53248,53760)  row-mask floats (never overlaid)
#define SM_SHORTS 26880     // 53760 B -> 3 blocks/CU

__device__ __forceinline__ short f2b(float f) {   // fp32 -> bf16 RNE
    unsigned u = __float_as_uint(f);
    u += 0x7fffu + ((u >> 16) & 1u);
    return (short)(u >> 16);
}
__device__ __forceinline__ float b2f(short h) {   // bf16 -> fp32 exact
    return __uint_as_float(((unsigned)(unsigned short)h) << 16);
}

// ---- K1: one-time weight hi/lo split into d_ws (tiny, off hot path) ----
__global__ void prep_weights(const float* __restrict__ W1,
                             const float* __restrict__ Wh0,
                             const float* __restrict__ Wh1,
                             short* __restrict__ ws)
{
    const int stride = gridDim.x * blockDim.x;
    const int tid = blockIdx.x * blockDim.x + threadIdx.x;
    for (int idx = tid; idx < 64 * 96; idx += stride) {       // W1^T + K-pad
        int c = idx / 96, k = idx - c * 96;
        float w = (k < FEAT) ? W1[k * 64 + c] : 0.f;
        short hi = f2b(w);
        ws[WT1H + idx] = hi;
        ws[WT1L + idx] = f2b(w - b2f(hi));
    }
    for (int idx = tid; idx < 32 * 64; idx += stride) {       // Wh0^T
        int c = idx >> 6, k = idx & 63;
        float w = Wh0[k * 32 + c];
        short hi = f2b(w);
        ws[WT2H + idx] = hi;
        ws[WT2L + idx] = f2b(w - b2f(hi));
    }
    for (int idx = tid; idx < 32 * 32; idx += stride) {       // Wh1^T
        int c = idx >> 5, k = idx & 31;
        float w = Wh1[k * 32 + c];
        short hi = f2b(w);
        ws[WT3H + idx] = hi;
        ws[WT3L + idx] = f2b(w - b2f(hi));
    }
}

// unpack 8 packed (hi<<16|lo) dwords -> two bf16x8 fragments
__device__ __forceinline__ void unpack8(const unsigned* p, bf16x8& hi, bf16x8& lo) {
    union { bf16x8 v; unsigned u[4]; } H, L;
    #pragma unroll
    for (int d = 0; d < 4; ++d) {
        H.u[d] = __builtin_amdgcn_perm(p[2 * d + 1], p[2 * d], 0x07060302u);
        L.u[d] = __builtin_amdgcn_perm(p[2 * d + 1], p[2 * d], 0x05040100u);
    }
    hi = H.v; lo = L.v;
}

__global__ __launch_bounds__(THREADS, 3)
void material_encoder_kernel(const float* __restrict__ inp,
                             const float* __restrict__ shiftp,
                             const short* __restrict__ ws,
                             const float* __restrict__ b1,
                             const float* __restrict__ bh0,
                             const float* __restrict__ bh1,
                             float* __restrict__ out,
                             int nrows)
{
    __shared__ __align__(16) short sm[SM_SHORTS];
    unsigned* scr = (unsigned*)((char*)sm + 36864) + (threadIdx.x >> 6) * 1024;
    float* maskf  = (float*)((char*)sm + 53248);

    const int t    = threadIdx.x;
    const int lane = t & 63;
    const int wv   = t >> 6;
    const int lr   = lane & 15;        // A-row / B-col / C-col index
    const int lq   = (lane >> 4) & 3;  // lane quarter

    float* xw = (float*)((char*)sm + wv * 10624);   // this wave's 32-row chunk

    // ---- phase A: wave-local coalesced x stage (10 full + 24-lane tail) ----
    f32x4 xreg[11];
    {
        const f32x4* __restrict__ src4 = (const f32x4*)
            (inp + (long long)blockIdx.x * (RPB * FEAT) + wv * (32 * FEAT));
        #pragma unroll
        for (int r = 0; r < 10; ++r) xreg[r] = src4[r * 64 + lane];
        if (lane < 24) xreg[10] = src4[640 + lane];
    }
    // weight image loads issued now; consumed after bar1 (latency hidden)
    f32x4 wreg[9];
    {
        const f32x4* __restrict__ wsrc = (const f32x4*)ws;
        #pragma unroll
        for (int it = 0; it < 9; ++it) wreg[it] = wsrc[it * THREADS + t];
    }
    {
        f32x4* xdst = (f32x4*)xw;
        #pragma unroll
        for (int r = 0; r < 10; ++r) xdst[r * 64 + lane] = xreg[r];
        if (lane < 24) xdst[640 + lane] = xreg[10];
    }

    // biases per lane (L2-cached)
    float bias1[4], bias2[2], bias3[2];
    #pragma unroll
    for (int n = 0; n < 4; ++n) bias1[n] = b1[lr + 16 * n];
    #pragma unroll
    for (int n = 0; n < 2; ++n) { bias2[n] = bh0[lr + 16 * n]; bias3[n] = bh1[lr + 16 * n]; }
    const float sh = shiftp[0];
    const int Rw = blockIdx.x * RPB + wv * 32;

    // ---- A fragments (x+shift) hi/lo from own chunk (same-wave DS order) ----
    // frag layout (16x16x32): row = lr, k = 8*lq + i (+32*s); trunc-hi split
    // k>=83 clamps to 82: duplicate finite x * zeroed W-pad -> 0
    // bank = (19*lr + 8*lq + C) mod 32 -> exact 2-way = free
    bf16x8 a1h[2][3], a1l[2][3];
    float nzm[2];
    #pragma unroll
    for (int m = 0; m < 2; ++m) {
        const float* __restrict__ xr = xw + (16 * m + lr) * FEAT;
        float nz = 0.f;
        #pragma unroll
        for (int s = 0; s < 3; ++s) {
            const int k0 = 32 * s + 8 * lq;
            bf16x8 fh, fl;
            #pragma unroll
            for (int i = 0; i < 8; ++i) {
                int kk = k0 + i;
                kk = (kk < FEAT) ? kk : (FEAT - 1);
                const float x = xr[kk];
                nz = fmaxf(nz, fabsf(x));
                const float xs = x + sh;
                const unsigned u = __float_as_uint(xs);
                fh[i] = (short)(u >> 16);            // truncation hi
                fl[i] = f2b(xs - __uint_as_float(u & 0xffff0000u));
            }
            a1h[m][s] = fh;
            a1l[m][s] = fl;
        }
        nzm[m] = nz;
    }
    #pragma unroll
    for (int m = 0; m < 2; ++m) {     // full-row max across the 4 k-quarters
        nzm[m] = fmaxf(nzm[m], __shfl_xor(nzm[m], 16));
        nzm[m] = fmaxf(nzm[m], __shfl_xor(nzm[m], 32));
    }
    if (lq == 0) {                    // mask region never overlaid
        maskf[wv * 32 + lr]      = nzm[0];
        maskf[wv * 32 + 16 + lr] = nzm[1];
    }

    __syncthreads();   // bar1: all x reads done -> weights may overlay [0,36864)

    {
        f32x4* wdst = (f32x4*)sm;
        #pragma unroll
        for (int it = 0; it < 9; ++it) wdst[it * THREADS + t] = wreg[it];
    }
    __syncthreads();   // bar2: weight image ready

    // ---- layer 1: 2(M) x 4(N) x 3(K) x 3 split-terms ----
    f32x4 acc[2][4];
    #pragma unroll
    for (int m = 0; m < 2; ++m)
        #pragma unroll
        for (int n = 0; n < 4; ++n)
            acc[m][n] = (f32x4){bias1[n], bias1[n], bias1[n], bias1[n]};

    #pragma unroll
    for (int s = 0; s < 3; ++s)
        #pragma unroll
        for (int n = 0; n < 4; ++n) {
            bf16x8 bh = *(const bf16x8*)&sm[WT1H + (lr + 16 * n) * 96 + 32 * s + 8 * lq];
            bf16x8 bl = *(const bf16x8*)&sm[WT1L + (lr + 16 * n) * 96 + 32 * s + 8 * lq];
            #pragma unroll
            for (int m = 0; m < 2; ++m) {
                acc[m][n] = __builtin_amdgcn_mfma_f32_16x16x32_bf16(a1h[m][s], bh, acc[m][n], 0, 0, 0);
                acc[m][n] = __builtin_amdgcn_mfma_f32_16x16x32_bf16(a1l[m][s], bh, acc[m][n], 0, 0, 0);
                acc[m][n] = __builtin_amdgcn_mfma_f32_16x16x32_bf16(a1h[m][s], bl, acc[m][n], 0, 0, 0);
            }
        }

    // ---- layer 2 via per-wave packed scratch (x dead; same-wave DS order) ----
    f32x4 acc2[2][2];
    #pragma unroll
    for (int m = 0; m < 2; ++m)
        #pragma unroll
        for (int n = 0; n < 2; ++n)
            acc2[m][n] = (f32x4){bias2[n], bias2[n], bias2[n], bias2[n]};

    #pragma unroll
    for (int s = 0; s < 2; ++s) {
        // write chunk s (h-dims 32s..32s+31) as packed hi|lo u32, [32][32]
        #pragma unroll
        for (int m = 0; m < 2; ++m)
            #pragma unroll
            for (int np = 0; np < 2; ++np)
                #pragma unroll
                for (int r = 0; r < 4; ++r) {
                    const float hv = fmaxf(acc[m][2 * s + np][r], 0.f);
                    const unsigned u = __float_as_uint(hv);
                    const unsigned hiu = u & 0xffff0000u;
                    const unsigned lo16 =
                        (unsigned short)f2b(hv - __uint_as_float(hiu));
                    scr[(16 * m + 4 * lq + r) * 32 + lr + 16 * np] = hiu | lo16;
                }
        // read A-frags (same-wave DS ordering; no barrier)
        bf16x8 a2h[2], a2l[2];
        #pragma unroll
        for (int m = 0; m < 2; ++m) {
            unsigned p[8];
            *(u32x4*)&p[0] = *(const u32x4*)&scr[(lr + 16 * m) * 32 + 8 * lq];
            *(u32x4*)&p[4] = *(const u32x4*)&scr[(lr + 16 * m) * 32 + 8 * lq + 4];
            unpack8(p, a2h[m], a2l[m]);
        }
        #pragma unroll
        for (int n = 0; n < 2; ++n) {
            bf16x8 bh = *(const bf16x8*)&sm[WT2H + (lr + 16 * n) * 64 + 32 * s + 8 * lq];
            bf16x8 bl = *(const bf16x8*)&sm[WT2L + (lr + 16 * n) * 64 + 32 * s + 8 * lq];
            #pragma unroll
            for (int m = 0; m < 2; ++m) {
                acc2[m][n] = __builtin_amdgcn_mfma_f32_16x16x32_bf16(a2h[m], bh, acc2[m][n], 0, 0, 0);
                acc2[m][n] = __builtin_amdgcn_mfma_f32_16x16x32_bf16(a2l[m], bh, acc2[m][n], 0, 0, 0);
                acc2[m][n] = __builtin_amdgcn_mfma_f32_16x16x32_bf16(a2h[m], bl, acc2[m][n], 0, 0, 0);
            }
        }
    }

    // ---- layer 3: g through the same scratch (reused, same-wave order) ----
    f32x4 acc3[2][2];
    #pragma unroll
    for (int m = 0; m < 2; ++m)
        #pragma unroll
        for (int n = 0; n < 2; ++n)
            acc3[m][n] = (f32x4){bias3[n], bias3[n], bias3[n], bias3[n]};

    #pragma unroll
    for (int m = 0; m < 2; ++m)
        #pragma unroll
        for (int n = 0; n < 2; ++n)
            #pragma unroll
            for (int r = 0; r < 4; ++r) {
                const float gv = fmaxf(acc2[m][n][r], 0.f);
                const unsigned u = __float_as_uint(gv);
                const unsigned hiu = u & 0xffff0000u;
                const unsigned lo16 =
                    (unsigned short)f2b(gv - __uint_as_float(hiu));
                scr[(16 * m + 4 * lq + r) * 32 + lr + 16 * n] = hiu | lo16;
            }
    {
        bf16x8 a3h[2], a3l[2];
        #pragma unroll
        for (int m = 0; m < 2; ++m) {
            unsigned p[8];
            *(u32x4*)&p[0] = *(const u32x4*)&scr[(lr + 16 * m) * 32 + 8 * lq];
            *(u32x4*)&p[4] = *(const u32x4*)&scr[(lr + 16 * m) * 32 + 8 * lq + 4];
            unpack8(p, a3h[m], a3l[m]);
        }
        #pragma unroll
        for (int n = 0; n < 2; ++n) {
            bf16x8 bh = *(const bf16x8*)&sm[WT3H + (lr + 16 * n) * 32 + 8 * lq];
            bf16x8 bl = *(const bf16x8*)&sm[WT3L + (lr + 16 * n) * 32 + 8 * lq];
            #pragma unroll
            for (int m = 0; m < 2; ++m) {
                acc3[m][n] = __builtin_amdgcn_mfma_f32_16x16x32_bf16(a3h[m], bh, acc3[m][n], 0, 0, 0);
                acc3[m][n] = __builtin_amdgcn_mfma_f32_16x16x32_bf16(a3l[m], bh, acc3[m][n], 0, 0, 0);
                acc3[m][n] = __builtin_amdgcn_mfma_f32_16x16x32_bf16(a3h[m], bl, acc3[m][n], 0, 0, 0);
            }
        }
    }

    // ---- relu + row L2 norm (reduce over cols = over lr lanes) + mask ----
    float er[2][2][4];
    float ssq[2][4];
    #pragma unroll
    for (int m = 0; m < 2; ++m)
        #pragma unroll
        for (int r = 0; r < 4; ++r) ssq[m][r] = 0.f;
    #pragma unroll
    for (int m = 0; m < 2; ++m)
        #pragma unroll
        for (int n = 0; n < 2; ++n)
            #pragma unroll
            for (int r = 0; r < 4; ++r) {
                float e = fmaxf(acc3[m][n][r], 0.f);
                er[m][n][r] = e;
                ssq[m][r] = fmaf(e, e, ssq[m][r]);
            }
    #pragma unroll
    for (int msk = 1; msk <= 8; msk <<= 1)
        #pragma unroll
        for (int m = 0; m < 2; ++m)
            #pragma unroll
            for (int r = 0; r < 4; ++r)
                ssq[m][r] += __shfl_xor(ssq[m][r], msk);

    const float* maskp = maskf + wv * 32;
    f32x4 mk[2];
    mk[0] = *(const f32x4*)&maskp[4 * lq];
    mk[1] = *(const f32x4*)&maskp[16 + 4 * lq];

    float sc[2][4];
    #pragma unroll
    for (int m = 0; m < 2; ++m)
        #pragma unroll
        for (int r = 0; r < 4; ++r)
            // rsqrt(max(ss,1e-24)) == 1/max(sqrt(ss),1e-12)
            sc[m][r] = (mk[m][r] != 0.f) ? rsqrtf(fmaxf(ssq[m][r], 1e-24f)) : 0.f;

    // ---- store 3 copies (quarter-wave 64B segments) ----
    const int osz = nrows * LAT;                 // 64M, fits int
    float* __restrict__ ob = out + (long long)Rw * LAT;
    #pragma unroll
    for (int m = 0; m < 2; ++m)
        #pragma unroll
        for (int r = 0; r < 4; ++r) {
            const int ro = (16 * m + 4 * lq + r) * LAT;
            #pragma unroll
            for (int n = 0; n < 2; ++n) {
                const float vv = er[m][n][r] * sc[m][r];
                const int cc = ro + lr + 16 * n;
                ob[cc]           = vv;
                ob[osz + cc]     = vv;
                ob[2 * osz + cc] = vv;
            }
        }
}

extern "C" void kernel_launch(void* const* d_in, const int* in_sizes, int n_in,
                              void* d_out, int out_size, void* d_ws, size_t ws_size,
                              hipStream_t stream) {
    const float* inp    = (const float*)d_in[0];
    const float* shiftp = (const float*)d_in[1];
    const float* W1     = (const float*)d_in[2];
    const float* b1     = (const float*)d_in[3];
    const float* Wh0    = (const float*)d_in[4];
    const float* bh0    = (const float*)d_in[5];
    const float* Wh1    = (const float*)d_in[6];
    const float* bh1    = (const float*)d_in[7];
    float* out = (float*)d_out;
    short* ws  = (short*)d_ws;

    const int nrows = in_sizes[0] / FEAT;      // 2,000,000 = 128 * 15625
    const int blocks = nrows / RPB;            // exact

    prep_weights<<<dim3(24), dim3(256), 0, stream>>>(W1, Wh0, Wh1, ws);
    material_encoder_kernel<<<dim3(blocks), dim3(THREADS), 0, stream>>>(
        inp, shiftp, ws, b1, bh0, bh1, out, nrows);
}